// Round 10
// baseline (469.988 us; speedup 1.0000x reference)
//
#include <hip/hip_runtime.h>

#define NEG_INF -1e30f

typedef __attribute__((ext_vector_type(8))) __bf16 bf16x8;
typedef __attribute__((ext_vector_type(4))) float f32x4;

constexpr int Bb = 16, T = 800, D = 512, V = 5000, L = 100;
constexpr int ROWS = Bb * T;        // 12800
constexpr int S = 2 * L + 1;        // 201
constexpr int SP = 208;             // padded S (13*16)
constexpr int VP = 5120;            // V padded to 128
constexpr int NCB = VP / 128;       // 40 col-blocks (GEMM)
constexpr int NRB = ROWS / 128;     // 100 row-blocks
constexpr int CH = 16;              // DP ring: timesteps per chunk (= one MFMA m-tile)
constexpr int RW = 212;             // DP ring row width (floats)
constexpr int CS = CH * RW;         // floats per ring buffer
constexpr int NCH = T / CH;         // 50 chunks cover t = 0..799

// float -> bf16 bits, round-to-nearest-even
static __device__ __forceinline__ unsigned short f2bf(float x) {
  union { float f; unsigned u; } v; v.f = x;
  unsigned r = (v.u + 0x7FFFu + ((v.u >> 16) & 1u)) >> 16;
  return (unsigned short)r;
}

// wave_shr:1 (0x138): lane i gets lane i-1; lane 0 (bound_ctrl=0) -> old = NEG_INF
static __device__ __forceinline__ float dpp_shr1_neginf(float x) {
  return __int_as_float(__builtin_amdgcn_update_dpp(
      __float_as_int(NEG_INF), __float_as_int(x), 0x138, 0xF, 0xF, false));
}

// ---- hs fp32 -> bf16 (row-major [12800][512]) ----
__global__ __launch_bounds__(256) void k_conv_hs(const float* __restrict__ hs,
                                                 unsigned short* __restrict__ A) {
  int i = blockIdx.x * 256 + threadIdx.x;
  float4 f = ((const float4*)hs)[i];
  ushort4 o;
  o.x = f2bf(f.x); o.y = f2bf(f.y); o.z = f2bf(f.z); o.w = f2bf(f.w);
  ((ushort4*)A)[i] = o;
}

// ---- W [512][5000] fp32 -> Wt [5120][512] bf16 (transposed, pad rows zero) ----
__global__ __launch_bounds__(256) void k_transW(const float* __restrict__ W,
                                                unsigned short* __restrict__ Wt) {
  __shared__ float tile[64][65];
  int v0 = blockIdx.x * 64, k0 = blockIdx.y * 64;
  int tl = threadIdx.x & 63, th = threadIdx.x >> 6;
#pragma unroll
  for (int i = 0; i < 16; i++) {
    int k = k0 + th + i * 4;
    int v = v0 + tl;
    tile[th + i * 4][tl] = (v < V) ? W[(size_t)k * V + v] : 0.f;
  }
  __syncthreads();
#pragma unroll
  for (int i = 0; i < 16; i++) {
    int v = v0 + th + i * 4;
    int k = k0 + tl;
    Wt[(size_t)v * D + k] = f2bf(tile[tl][th + i * 4]);
  }
}

// ---- FUSED kernel ----
// blocks 0..15:    CTC DP. Waves 1-3 produce gathered-logit rows (MFMA) into a
//                  double-buffered LDS ring; wave 0 runs the serial DP chain.
// blocks 16..4015: 128x128 GEMM + per-row softmax partials (XOR-swizzled LDS).
// Both paths overlay one 34816-byte static LDS block.
__global__ __launch_bounds__(256) void k_fused(const unsigned short* __restrict__ A,
                                               const unsigned short* __restrict__ Wt,
                                               const float* __restrict__ bias,
                                               const int* __restrict__ labels,
                                               const int* __restrict__ hlens,
                                               const int* __restrict__ llens,
                                               float* __restrict__ partM,
                                               float* __restrict__ partS,
                                               float* __restrict__ rawtot) {
  __shared__ __align__(16) char smem[34816];

  int blk = blockIdx.x;
  int tid = threadIdx.x;
  int lane = tid & 63, w = tid >> 6;
  int q = lane >> 4, c = lane & 15;

  if (blk < Bb) {
    // ===================== DP path =====================
    float* ring = (float*)smem;                      // 2 * CS * 4 = 27136 B
    int b = blk;
    int bT = b * T, bL = b * L;
    int hl = hlens[b];

    // producer: compute one 16(t) x 16(s) gathered-logit tile into the ring
    //   A-fragment row = t0 + c (m), B row = Wt[ext[s0+c]] (n), K = 512
    auto produce_tile = [&](int t0, int s0, float* dst) {
      int s = s0 + c;
      int ev = (s < S && (s & 1)) ? labels[bL + (s >> 1)] : 0;
      const unsigned short* Brow = Wt + (size_t)ev * D;
      const unsigned short* Arow = A + (size_t)(bT + t0 + c) * D;
      f32x4 acc = {0.f, 0.f, 0.f, 0.f};
#pragma unroll
      for (int kk = 0; kk < D; kk += 32) {
        bf16x8 a = *(const bf16x8*)(Arow + kk + q * 8);
        bf16x8 bb = *(const bf16x8*)(Brow + kk + q * 8);
        acc = __builtin_amdgcn_mfma_f32_16x16x32_bf16(a, bb, acc, 0, 0, 0);
      }
      float bs = bias[ev];
#pragma unroll
      for (int r = 0; r < 4; r++)
        dst[(q * 4 + r) * RW + s0 + c] = acc[r] + bs;
    };

    // stage chunk 0 (t = 0..15) with ALL 4 waves
    for (int tile = w; tile < 13; tile += 4) produce_tile(0, tile * 16, ring);
    __syncthreads();

    // DP lane setup (wave 0)
    int col = 4 * lane < SP ? 4 * lane : SP - 4;   // lanes >=52 clamp; garbage flows only upward in s
    int i0 = (2 * lane < L) ? 2 * lane : L - 1;
    int i1 = (2 * lane + 1 < L) ? 2 * lane + 1 : L - 1;
    int im = (lane >= 1) ? 2 * lane - 1 : 0; im = im < L ? im : L - 1;
    int lab0 = labels[bL + i0];
    int lab1 = labels[bL + i1];
    int labm = labels[bL + im];
    bool sk1 = (lane >= 1) && (lab0 != 0) && (lab0 != labm);
    bool sk3 = (lab1 != 0) && (lab1 != lab0);

    float a0 = NEG_INF, a1 = NEG_INF, a2 = NEG_INF, a3 = NEG_INF;
    if (w == 0) {
      f32x4 g0 = *(const f32x4*)(ring + col);   // chunk 0 row 0 = t 0
      a0 = (lane == 0) ? g0.x : NEG_INF;
      a1 = (lane == 0) ? g0.y : NEG_INF;
    }

#define DP_STEP(G) {                                                          \
    float p3 = dpp_shr1_neginf(a3);              /* alpha[4l-1] */            \
    float s1 = sk1 ? p3 : NEG_INF;                                            \
    float m0 = fmaxf(a0, p3);                                                 \
    float n0 = m0 + __logf(__expf(a0 - m0) + __expf(p3 - m0)) + (G).x;        \
    float m1 = fmaxf(fmaxf(a1, a0), s1);                                      \
    float n1 = m1 + __logf(__expf(a1 - m1) + __expf(a0 - m1) + __expf(s1 - m1)) + (G).y; \
    float m2 = fmaxf(a2, a1);                                                 \
    float n2 = m2 + __logf(__expf(a2 - m2) + __expf(a1 - m2)) + (G).z;        \
    float s3 = sk3 ? a1 : NEG_INF;                                            \
    float m3 = fmaxf(fmaxf(a3, a2), s3);                                      \
    float n3 = m3 + __logf(__expf(a3 - m3) + __expf(a2 - m3) + __expf(s3 - m3)) + (G).w; \
    a0 = n0; a1 = n1; a2 = n2; a3 = n3; }

    for (int ch = 0; ch < NCH; ch++) {
      if (w != 0) {
        // waves 1-3: produce chunk ch+1 into the other buffer
        if (ch + 1 < NCH) {
          float* dst = ring + ((ch + 1) & 1) * CS;
          int t0 = (ch + 1) * CH;
          for (int tile = w - 1; tile < 13; tile += 3) produce_tile(t0, tile * 16, dst);
        }
      } else {
        // wave 0: up to 16 DP steps from the current buffer
        const float* bp = ring + (ch & 1) * CS;
        int j0 = (ch == 0) ? 1 : 0;          // t=0 was the init row
#pragma unroll
        for (int j = 0; j < CH; j++) {
          int t = ch * CH + j;
          if (j >= j0 && t < hl) {           // wave-uniform predicate
            f32x4 G = *(const f32x4*)(bp + j * RW + col);
            DP_STEP(G)
          }
        }
      }
      __syncthreads();
    }
#undef DP_STEP

    if (w == 0) {
      // extract alpha[2ll], alpha[2ll-1] via shuffles
      int ll = llens[b];
      int s1i = 2 * ll, s2i = 2 * ll - 1;
      int c1 = s1i & 3, c2 = s2i & 3;
      float cand1 = c1 == 0 ? a0 : c1 == 1 ? a1 : c1 == 2 ? a2 : a3;
      float cand2 = c2 == 0 ? a0 : c2 == 1 ? a1 : c2 == 2 ? a2 : a3;
      float v1 = __shfl(cand1, s1i >> 2);
      float v2 = __shfl(cand2, s2i >> 2);
      if (lane == 0) {
        float m = fmaxf(v1, v2);
        rawtot[b] = m + __logf(__expf(v1 - m) + __expf(v2 - m));
      }
    }
    return;
  }

  // ===================== GEMM path =====================
  unsigned short* As = (unsigned short*)smem;             // 128*64*2 = 16384
  unsigned short* Bs = (unsigned short*)(smem + 16384);   // 16384
  float* redM = (float*)(smem + 32768);                   // 2*128*4 = 1024
  float* redS = (float*)(smem + 33792);                   // 1024

  int gblk = blk - Bb;
  int cb = gblk % NCB, rb = gblk / NCB;
  int mh = w & 1, nh = w >> 1;
  int row0 = rb * 128, n0 = cb * 128;
  int lr = lane >> 3, lc = lane & 7;
  int oc = (lc ^ lr) * 8;    // XOR-swizzled global octet (bank-conflict-free LDS)

  f32x4 acc[4][4];
#pragma unroll
  for (int mt = 0; mt < 4; mt++)
#pragma unroll
    for (int nt = 0; nt < 4; nt++) acc[mt][nt] = (f32x4){0.f, 0.f, 0.f, 0.f};

  for (int kk = 0; kk < D; kk += 64) {
#pragma unroll
    for (int j = 0; j < 4; j++) {
      int i = w * 4 + j;
      const unsigned short* ga = A + (size_t)(row0 + i * 8 + lr) * D + kk + oc;
      __builtin_amdgcn_global_load_lds(
          (const __attribute__((address_space(1))) void*)ga,
          (__attribute__((address_space(3))) void*)(As + i * 512), 16, 0, 0);
      const unsigned short* gb = Wt + (size_t)(n0 + i * 8 + lr) * D + kk + oc;
      __builtin_amdgcn_global_load_lds(
          (const __attribute__((address_space(1))) void*)gb,
          (__attribute__((address_space(3))) void*)(Bs + i * 512), 16, 0, 0);
    }
    __syncthreads();
#pragma unroll
    for (int kq = 0; kq < 2; kq++) {
      int o = ((kq * 4 + q) ^ (c & 7)) * 8;
      bf16x8 af[4], bfr[4];
#pragma unroll
      for (int mt = 0; mt < 4; mt++)
        af[mt] = *(const bf16x8*)(As + (mh * 64 + mt * 16 + c) * 64 + o);
#pragma unroll
      for (int nt = 0; nt < 4; nt++)
        bfr[nt] = *(const bf16x8*)(Bs + (nh * 64 + nt * 16 + c) * 64 + o);
#pragma unroll
      for (int mt = 0; mt < 4; mt++)
#pragma unroll
        for (int nt = 0; nt < 4; nt++)
          acc[mt][nt] = __builtin_amdgcn_mfma_f32_16x16x32_bf16(af[mt], bfr[nt], acc[mt][nt], 0, 0, 0);
    }
    __syncthreads();
  }

  int vcb[4]; float bv[4];
#pragma unroll
  for (int nt = 0; nt < 4; nt++) {
    vcb[nt] = n0 + nh * 64 + nt * 16 + c;
    bv[nt] = (vcb[nt] < V) ? bias[vcb[nt]] : 0.f;
  }
#pragma unroll
  for (int mt = 0; mt < 4; mt++) {
#pragma unroll
    for (int r = 0; r < 4; r++) {
      float x[4]; float m = NEG_INF;
#pragma unroll
      for (int nt = 0; nt < 4; nt++) {
        x[nt] = (vcb[nt] < V) ? (acc[mt][nt][r] + bv[nt]) : NEG_INF;
        m = fmaxf(m, x[nt]);
      }
#pragma unroll
      for (int o = 1; o < 16; o <<= 1) m = fmaxf(m, __shfl_xor(m, o));
      float s = 0.f;
#pragma unroll
      for (int nt = 0; nt < 4; nt++) s += __expf(x[nt] - m);
#pragma unroll
      for (int o = 1; o < 16; o <<= 1) s += __shfl_xor(s, o);
      if (c == 0) {
        int rloc = mh * 64 + mt * 16 + q * 4 + r;
        redM[nh * 128 + rloc] = m;
        redS[nh * 128 + rloc] = s;
      }
    }
  }
  __syncthreads();
  if (tid < 128) {
    float m0 = redM[tid], m1 = redM[128 + tid];
    float mm = fmaxf(m0, m1);
    float ss = redS[tid] * __expf(m0 - mm) + redS[128 + tid] * __expf(m1 - mm);
    partM[(size_t)cb * ROWS + row0 + tid] = mm;
    partS[(size_t)cb * ROWS + row0 + tid] = ss;
  }
}

// ---- combine 40 partials -> lse[row] ----
__global__ __launch_bounds__(256) void k_lse(const float* __restrict__ pM,
                                             const float* __restrict__ pS,
                                             float* __restrict__ lse) {
  int row = blockIdx.x * 256 + threadIdx.x;
  float m = pM[row], s = pS[row];
  for (int cb = 1; cb < NCB; cb++) {
    float M2 = pM[(size_t)cb * ROWS + row], S2 = pS[(size_t)cb * ROWS + row];
    float mn = fmaxf(m, M2);
    s = s * __expf(m - mn) + S2 * __expf(M2 - mn);
    m = mn;
  }
  lse[row] = m + __logf(s);
}

// ---- final: tot[b] = rawtot[b] - sum_{t<hl} lse[b,t]; out = mean(-tot) ----
__global__ __launch_bounds__(1024) void k_final(const float* __restrict__ lse,
                                                const float* __restrict__ rawtot,
                                                const int* __restrict__ hlens,
                                                float* __restrict__ out) {
  __shared__ float acc[Bb];
  int w = threadIdx.x >> 6, l = threadIdx.x & 63;  // 16 waves, one per b
  int hl = hlens[w];
  float s = 0.f;
  for (int t = l; t < hl; t += 64) s += lse[w * T + t];
#pragma unroll
  for (int o = 1; o < 64; o <<= 1) s += __shfl_xor(s, o);
  if (l == 0) acc[w] = rawtot[w] - s;
  __syncthreads();
  if (threadIdx.x == 0) {
    float m = 0.f;
    for (int i = 0; i < Bb; i++) m += acc[i];
    out[0] = -m / (float)Bb;
  }
}

extern "C" void kernel_launch(void* const* d_in, const int* in_sizes, int n_in,
                              void* d_out, int out_size, void* d_ws, size_t ws_size,
                              hipStream_t stream) {
  const float* hs    = (const float*)d_in[0];
  const float* W     = (const float*)d_in[1];
  const float* bias  = (const float*)d_in[2];
  const int* hlens   = (const int*)d_in[3];
  const int* labels  = (const int*)d_in[4];
  const int* llens   = (const int*)d_in[5];
  float* out = (float*)d_out;

  char* ws = (char*)d_ws;
  unsigned short* A    = (unsigned short*)(ws);              // 12800*512*2 = 13,107,200
  unsigned short* Wt   = (unsigned short*)(ws + 13107200);   // 5120*512*2  =  5,242,880
  float*          partM= (float*)(ws + 18350080);            // 40*12800*4  =  2,048,000
  float*          partS= (float*)(ws + 20398080);            // 40*12800*4  =  2,048,000
  float*          lse  = (float*)(ws + 22446080);            // 12800*4     =     51,200
  float*          rawtot=(float*)(ws + 22497280);            // 16*4

  k_conv_hs<<<ROWS * D / 1024, 256, 0, stream>>>(hs, A);
  k_transW<<<dim3(VP / 64, D / 64), 256, 0, stream>>>(W, Wt);
  k_fused<<<Bb + NCB * NRB, 256, 0, stream>>>(A, Wt, bias, labels, hlens, llens,
                                              partM, partS, rawtot);
  k_lse<<<ROWS / 256, 256, 0, stream>>>(partM, partS, lse);
  k_final<<<1, 1024, 0, stream>>>(lse, rawtot, hlens, out);

  (void)in_sizes; (void)n_in; (void)out_size; (void)ws_size;
}